// Round 15
// baseline (115.589 us; speedup 1.0000x reference)
//
#include <hip/hip_runtime.h>

#define NPIX   65536
#define HB     128
#define EPSF   1e-6f
#define ROWB   80              /* 32 px * 2B = 64B data + 16B pad (5 x 16B) */
#define MATB   (HB * ROWB)     /* 10240 B per matrix */
#define BUFB   (3 * MATB)      /* 30720 B per buffer set */
#define PPW    24576           /* parts u32 words per block: 3*128*128/2 */

typedef _Float16 half8  __attribute__((ext_vector_type(8)));
typedef __fp16   fp16x2 __attribute__((ext_vector_type(2)));
typedef float    f32x16 __attribute__((ext_vector_type(16)));
typedef float    f32x2  __attribute__((ext_vector_type(2)));

__device__ __forceinline__ unsigned pk2(float a, float b) {
    union { fp16x2 h; unsigned u; } cv;
    cv.h = __builtin_amdgcn_cvt_pkrtz(a, b);
    return cv.u;
}

/* ---------------- kernel 1: pipelined shared-field MFMA histogram -----
 * (byte-identical body to r14's best: 76.3-77.3 us measured)
 * 256 thr / 4 waves, 32-px regions, dbuf LDS, one barrier per region,
 * T3 issue order {8 ds_reads -> gen under them -> 12-MFMA cluster},
 * setprio on MFMA clusters, b32 gen writes, mat2 gen in barrier shadow.
 * r15 change is OUTSIDE this kernel: nchunk 64->32 (parts 25 MB). */
__global__ __launch_bounds__(256, 2) void hist_mfma(
    const float* __restrict__ pred, const float* __restrict__ tgt,
    unsigned* __restrict__ parts, float* __restrict__ norms, int nchunk)
{
    __shared__ char smat[2 * BUFB];               /* 61440 B */
    __shared__ float wsumS[4];

    const int t    = threadIdx.x;
    const int lane = t & 63;
    const int wave = t >> 6;
    const int chunk = blockIdx.x % nchunk;
    const int ib    = blockIdx.x / nchunk;        /* img*4 + b */
    const int b     = ib & 3;
    const int img   = ib >> 2;
    const int kchunk = NPIX / nchunk;
    const int nreg   = kchunk >> 5;               /* 32-px regions, even */

    const float* __restrict__ base = (img ? tgt : pred) + (size_t)b * 3 * NPIX;
    const float* __restrict__ Rp = base;
    const float* __restrict__ Gp = base + NPIX;
    const float* __restrict__ Bp = base + 2 * NPIX;

    /* gen role */
    const int   i16     = lane & 15;              /* px pair index */
    const int   r4      = lane >> 4;              /* row within 16-group */
    const int   rowbase = wave * 4 + r4;          /* 0..15 */
    const float MU0     = (float)rowbase * (300.0f / 127.0f) - 150.0f;
    const float MUSTEP  = 16.0f * (300.0f / 127.0f);
    char* genp0 = smat + rowbase * ROWB + i16 * 4;
    char* genp1 = genp0 + BUFB;

    /* mfma role */
    const int ti2 = wave >> 1;
    const int tj2 = wave & 1;

    f32x16 acc[3][2][2];
#pragma unroll
    for (int g = 0; g < 3; ++g)
#pragma unroll
        for (int i = 0; i < 2; ++i)
#pragma unroll
            for (int j = 0; j < 2; ++j)
#pragma unroll
                for (int r = 0; r < 16; ++r) acc[g][i][j][r] = 0.0f;

    const int n0 = chunk * kchunk;

    f32x2 Ra, Ga, Ba, Rb, Gb, Bb;                 /* load ping-pong */
    f32x2 ddrg, ddrb, ddgb, rw2;                  /* current scalars */

    auto issue_ld = [&](int reg, f32x2& R, f32x2& G, f32x2& B) {
        const int n = n0 + reg * 32 + 2 * i16;
        R = *reinterpret_cast<const f32x2*>(Rp + n);
        G = *reinterpret_cast<const f32x2*>(Gp + n);
        B = *reinterpret_cast<const f32x2*>(Bp + n);
    };

    auto scalars = [&](f32x2 R, f32x2 G, f32x2 B) {
        const float C = 34.65735902799726547086f;   /* 50 * ln2 */
        float r0 = fminf(fmaxf(R.x, 0.0f), 1.0f);
        float r1 = fminf(fmaxf(R.y, 0.0f), 1.0f);
        float g0 = fminf(fmaxf(G.x, 0.0f), 1.0f);
        float g1 = fminf(fmaxf(G.y, 0.0f), 1.0f);
        float b0 = fminf(fmaxf(B.x, 0.0f), 1.0f);
        float b1 = fminf(fmaxf(B.y, 0.0f), 1.0f);
        float lr0 = __builtin_amdgcn_logf(r0 + EPSF);
        float lr1 = __builtin_amdgcn_logf(r1 + EPSF);
        float lg0 = __builtin_amdgcn_logf(g0 + EPSF);
        float lg1 = __builtin_amdgcn_logf(g1 + EPSF);
        float lb0 = __builtin_amdgcn_logf(b0 + EPSF);
        float lb1 = __builtin_amdgcn_logf(b1 + EPSF);
        ddrg.x = (lr0 - lg0) * C;  ddrg.y = (lr1 - lg1) * C;
        ddrb.x = (lr0 - lb0) * C;  ddrb.y = (lr1 - lb1) * C;
        ddgb.x = (lg0 - lb0) * C;  ddgb.y = (lg1 - lb1) * C;
        const float s0 = __builtin_fmaf(r0, r0,
                          __builtin_fmaf(g0, g0,
                           __builtin_fmaf(b0, b0, EPSF)));
        const float s1 = __builtin_fmaf(r1, r1,
                          __builtin_fmaf(g1, g1,
                           __builtin_fmaf(b1, b1, EPSF)));
        rw2.x = __builtin_amdgcn_sqrtf(__builtin_amdgcn_sqrtf(s0));
        rw2.y = __builtin_amdgcn_sqrtf(__builtin_amdgcn_sqrtf(s1));
    };

    auto gen_mat = [&](char* bp, int mat, f32x2 dd) {
        float m = MU0;
#pragma unroll
        for (int s = 0; s < 8; ++s) {              /* rows rowbase + 16*s */
            const float ex = dd.x - m, ey = dd.y - m;
            const float tx = __builtin_fmaf(ex, ex, 1.0f);
            const float ty = __builtin_fmaf(ey, ey, 1.0f);
            const float vx = __builtin_amdgcn_rcpf(tx) * rw2.x;
            const float vy = __builtin_amdgcn_rcpf(ty) * rw2.y;
            *reinterpret_cast<unsigned*>(bp + mat * MATB + s * 16 * ROWB)
                = pk2(vx, vy);
            m += MUSTEP;
        }
    };

    auto rd = [&](const char* mp, int matid, int row, int koff) -> half8 {
        return *reinterpret_cast<const half8*>(mp + matid * MATB
                                               + row * ROWB + koff);
    };

    /* region body, T3 order: reads -> gen under them -> MFMA cluster */
    auto body = [&](const char* mp, char* gp, bool dogen) {
        const int kbase = (lane >> 5) << 4;       /* 0 or 16 bytes */
        const int r0 = ti2 * 64 + (lane & 31);
        const int c0 = tj2 * 64 + (lane & 31);

        /* ---- k-step 0: 8 reads || gen mat0 || 12 MFMA ---- */
        {
            half8 a0  = rd(mp, 0, r0,      kbase);
            half8 a1  = rd(mp, 0, r0 + 32, kbase);
            half8 p0  = rd(mp, 1, c0,      kbase);
            half8 p1  = rd(mp, 1, c0 + 32, kbase);
            half8 q0  = rd(mp, 2, c0,      kbase);
            half8 q1  = rd(mp, 2, c0 + 32, kbase);
            half8 bb0 = rd(mp, 1, r0,      kbase);
            half8 bb1 = rd(mp, 1, r0 + 32, kbase);
            if (dogen) gen_mat(gp, 0, ddrg);
            __builtin_amdgcn_s_setprio(1);
            acc[0][0][0] = __builtin_amdgcn_mfma_f32_32x32x16_f16(a0, p0, acc[0][0][0], 0, 0, 0);
            acc[0][0][1] = __builtin_amdgcn_mfma_f32_32x32x16_f16(a0, p1, acc[0][0][1], 0, 0, 0);
            acc[0][1][0] = __builtin_amdgcn_mfma_f32_32x32x16_f16(a1, p0, acc[0][1][0], 0, 0, 0);
            acc[0][1][1] = __builtin_amdgcn_mfma_f32_32x32x16_f16(a1, p1, acc[0][1][1], 0, 0, 0);
            acc[1][0][0] = __builtin_amdgcn_mfma_f32_32x32x16_f16(a0, q0, acc[1][0][0], 0, 0, 0);
            acc[1][0][1] = __builtin_amdgcn_mfma_f32_32x32x16_f16(a0, q1, acc[1][0][1], 0, 0, 0);
            acc[1][1][0] = __builtin_amdgcn_mfma_f32_32x32x16_f16(a1, q0, acc[1][1][0], 0, 0, 0);
            acc[1][1][1] = __builtin_amdgcn_mfma_f32_32x32x16_f16(a1, q1, acc[1][1][1], 0, 0, 0);
            acc[2][0][0] = __builtin_amdgcn_mfma_f32_32x32x16_f16(bb0, q0, acc[2][0][0], 0, 0, 0);
            acc[2][0][1] = __builtin_amdgcn_mfma_f32_32x32x16_f16(bb0, q1, acc[2][0][1], 0, 0, 0);
            acc[2][1][0] = __builtin_amdgcn_mfma_f32_32x32x16_f16(bb1, q0, acc[2][1][0], 0, 0, 0);
            acc[2][1][1] = __builtin_amdgcn_mfma_f32_32x32x16_f16(bb1, q1, acc[2][1][1], 0, 0, 0);
            __builtin_amdgcn_s_setprio(0);
        }

        /* ---- k-step 1: 8 reads || gen mat1 || 12 MFMA ---- */
        {
            const int k1 = 32 + kbase;
            half8 a0  = rd(mp, 0, r0,      k1);
            half8 a1  = rd(mp, 0, r0 + 32, k1);
            half8 p0  = rd(mp, 1, c0,      k1);
            half8 p1  = rd(mp, 1, c0 + 32, k1);
            half8 q0  = rd(mp, 2, c0,      k1);
            half8 q1  = rd(mp, 2, c0 + 32, k1);
            half8 bb0 = rd(mp, 1, r0,      k1);
            half8 bb1 = rd(mp, 1, r0 + 32, k1);
            if (dogen) gen_mat(gp, 1, ddrb);
            __builtin_amdgcn_s_setprio(1);
            acc[0][0][0] = __builtin_amdgcn_mfma_f32_32x32x16_f16(a0, p0, acc[0][0][0], 0, 0, 0);
            acc[0][0][1] = __builtin_amdgcn_mfma_f32_32x32x16_f16(a0, p1, acc[0][0][1], 0, 0, 0);
            acc[0][1][0] = __builtin_amdgcn_mfma_f32_32x32x16_f16(a1, p0, acc[0][1][0], 0, 0, 0);
            acc[0][1][1] = __builtin_amdgcn_mfma_f32_32x32x16_f16(a1, p1, acc[0][1][1], 0, 0, 0);
            acc[1][0][0] = __builtin_amdgcn_mfma_f32_32x32x16_f16(a0, q0, acc[1][0][0], 0, 0, 0);
            acc[1][0][1] = __builtin_amdgcn_mfma_f32_32x32x16_f16(a0, q1, acc[1][0][1], 0, 0, 0);
            acc[1][1][0] = __builtin_amdgcn_mfma_f32_32x32x16_f16(a1, q0, acc[1][1][0], 0, 0, 0);
            acc[1][1][1] = __builtin_amdgcn_mfma_f32_32x32x16_f16(a1, q1, acc[1][1][1], 0, 0, 0);
            acc[2][0][0] = __builtin_amdgcn_mfma_f32_32x32x16_f16(bb0, q0, acc[2][0][0], 0, 0, 0);
            acc[2][0][1] = __builtin_amdgcn_mfma_f32_32x32x16_f16(bb0, q1, acc[2][0][1], 0, 0, 0);
            acc[2][1][0] = __builtin_amdgcn_mfma_f32_32x32x16_f16(bb1, q0, acc[2][1][0], 0, 0, 0);
            acc[2][1][1] = __builtin_amdgcn_mfma_f32_32x32x16_f16(bb1, q1, acc[2][1][1], 0, 0, 0);
            __builtin_amdgcn_s_setprio(0);
        }

        /* ---- tail: gen mat2 in the barrier shadow ---- */
        if (dogen) gen_mat(gp, 2, ddgb);
    };

    /* prologue: gen region 0 into buf0 */
    issue_ld(0, Ra, Ga, Ba);
    scalars(Ra, Ga, Ba);
    gen_mat(genp0, 0, ddrg);
    gen_mat(genp0, 1, ddrb);
    gen_mat(genp0, 2, ddgb);
    issue_ld(1, Rb, Gb, Bb);
    __syncthreads();

    for (int rg = 0; rg < nreg; rg += 2) {
        /* body A: MFMA reg rg (buf0) || gen reg rg+1 -> buf1 */
        scalars(Rb, Gb, Bb);
        issue_ld(min(rg + 2, nreg - 1), Ra, Ga, Ba);
        body(smat, genp1, true);
        __syncthreads();
        /* body B: MFMA reg rg+1 (buf1) || gen reg rg+2 -> buf0 */
        scalars(Ra, Ga, Ba);
        issue_ld(min(rg + 3, nreg - 1), Rb, Gb, Bb);
        body(smat + BUFB, genp0, rg + 2 < nreg);
        __syncthreads();
    }

    /* ---- epilogue A: pack f16 pairs, coalesced u32 stores.
     * word = (((g*4+wave)*2+i2)*2+j2)*8*64 + rh*64 + lane.
     * Consistent bijection; norms+Hellinger permutation-invariant. */
    unsigned* pb0 = parts + (size_t)blockIdx.x * PPW;
    float blksum = 0.0f;
#pragma unroll
    for (int g = 0; g < 3; ++g)
#pragma unroll
        for (int i2 = 0; i2 < 2; ++i2)
#pragma unroll
            for (int j2 = 0; j2 < 2; ++j2) {
                unsigned* wp = pb0
                    + (size_t)((((g * 4 + wave) * 2 + i2) * 2 + j2) * 8) * 64
                    + lane;
#pragma unroll
                for (int rh = 0; rh < 8; ++rh) {
                    wp[rh * 64] = pk2(acc[g][i2][j2][2 * rh],
                                      acc[g][i2][j2][2 * rh + 1]);
                    blksum += acc[g][i2][j2][2 * rh]
                            + acc[g][i2][j2][2 * rh + 1];
                }
            }

    /* ---- epilogue B: block contribution to norms[ib] ---- */
    for (int o = 32; o > 0; o >>= 1) blksum += __shfl_down(blksum, o, 64);
    if (lane == 0) wsumS[wave] = blksum;
    __syncthreads();
    if (t == 0)
        atomicAdd(&norms[ib], wsumS[0] + wsumS[1] + wsumS[2] + wsumS[3]);
}

/* ------- kernel 2: fused parts-reduce + Hellinger + loss + finalize ---
 * Last-block counter writes the final scalar (validated r13). */
__global__ __launch_bounds__(256) void reduce_loss(
    const unsigned* __restrict__ parts, const float* __restrict__ norms,
    float* __restrict__ acc, unsigned* __restrict__ cnt,
    float* __restrict__ out, int nchunk)
{
    const int i      = blockIdx.x * 256 + threadIdx.x;  /* < 98304 */
    const int comb12 = i >> 13;                         /* block-uniform */
    const int rest   = i & 8191;
    const int b      = comb12 / 3;
    const int g      = comb12 % 3;
    const unsigned* pp = parts + (size_t)(b * nchunk) * PPW + g * 8192 + rest;
    const unsigned* pt = parts + (size_t)((4 + b) * nchunk) * PPW + g * 8192 + rest;

    float hp0 = 0.0f, hp1 = 0.0f, ht0 = 0.0f, ht1 = 0.0f;
    int k = 0;
    for (; k + 8 <= nchunk; k += 8) {
#pragma unroll
        for (int j = 0; j < 8; ++j) {
            union { unsigned u; fp16x2 h; } a, c;
            a.u = pp[(size_t)(k + j) * PPW];
            c.u = pt[(size_t)(k + j) * PPW];
            hp0 += (float)a.h.x;  hp1 += (float)a.h.y;
            ht0 += (float)c.h.x;  ht1 += (float)c.h.y;
        }
    }
    for (; k < nchunk; ++k) {
        union { unsigned u; fp16x2 h; } a, c;
        a.u = pp[(size_t)k * PPW];
        c.u = pt[(size_t)k * PPW];
        hp0 += (float)a.h.x;  hp1 += (float)a.h.y;
        ht0 += (float)c.h.x;  ht1 += (float)c.h.y;
    }

    const float rp = __builtin_amdgcn_rcpf(norms[b] + EPSF);
    const float rt = __builtin_amdgcn_rcpf(norms[4 + b] + EPSF);
    const float d0 = __builtin_amdgcn_sqrtf(ht0 * rt)
                   - __builtin_amdgcn_sqrtf(hp0 * rp);
    const float d1 = __builtin_amdgcn_sqrtf(ht1 * rt)
                   - __builtin_amdgcn_sqrtf(hp1 * rp);
    float s = __builtin_fmaf(d0, d0, d1 * d1);
    for (int o = 32; o > 0; o >>= 1) s += __shfl_down(s, o, 64);
    __shared__ float wsum[4];
    if ((threadIdx.x & 63) == 0) wsum[threadIdx.x >> 6] = s;
    __syncthreads();
    if (threadIdx.x == 0) {
        atomicAdd(acc, wsum[0] + wsum[1] + wsum[2] + wsum[3]);
        __threadfence();
        const unsigned done = atomicAdd(cnt, 1u);
        if (done == gridDim.x - 1) {
            const float v = atomicAdd(acc, 0.0f);   /* coherent read */
            out[0] = __builtin_amdgcn_sqrtf(v)
                   * 0.70710678118654752440f * 0.25f;
        }
    }
}

extern "C" void kernel_launch(void* const* d_in, const int* in_sizes, int n_in,
                              void* d_out, int out_size, void* d_ws, size_t ws_size,
                              hipStream_t stream)
{
    const float* pred = (const float*)d_in[0];
    const float* tgt  = (const float*)d_in[1];
    float* ws  = (float*)d_ws;
    float* out = (float*)d_out;

    float*    norms = ws;             /* 8 floats                          */
    float*    acc   = ws + 8;         /* 1 float                           */
    unsigned* cnt   = (unsigned*)(ws + 9);      /* 1 u32                   */
    unsigned* parts = (unsigned*)(ws + 16);     /* 8*nchunk*PPW u32        */

    /* nchunk=32 -> 256 blocks = 1/CU, parts 25 MB (tail halves) */
    int nchunk = 32;
    while (nchunk > 1) {
        const size_t need = (16 + (size_t)8 * nchunk * PPW) * sizeof(float);
        if (need <= ws_size) break;
        nchunk >>= 1;
    }

    (void)hipMemsetAsync(ws, 0, 16 * sizeof(float), stream); /* norms+acc+cnt */

    hist_mfma<<<8 * nchunk, 256, 0, stream>>>(pred, tgt, parts, norms, nchunk);
    reduce_loss<<<12 * 8192 / 256, 256, 0, stream>>>(parts, norms, acc, cnt,
                                                     out, nchunk);
}

// Round 16
// 105.266 us; speedup vs baseline: 1.0981x; 1.0981x over previous
//
#include <hip/hip_runtime.h>

#define NPIX   65536
#define HB     128
#define EPSF   1e-6f
#define ROWB   80              /* 32 px * 2B = 64B data + 16B pad (5 x 16B) */
#define MATB   (HB * ROWB)     /* 10240 B per matrix */
#define BUFB   (3 * MATB)      /* 30720 B per buffer set */
#define PPW    24576           /* parts u32 words per block: 3*128*128/2 */

typedef _Float16 half8  __attribute__((ext_vector_type(8)));
typedef __fp16   fp16x2 __attribute__((ext_vector_type(2)));
typedef float    f32x16 __attribute__((ext_vector_type(16)));
typedef float    f32x2  __attribute__((ext_vector_type(2)));

__device__ __forceinline__ unsigned pk2(float a, float b) {
    union { fp16x2 h; unsigned u; } cv;
    cv.h = __builtin_amdgcn_cvt_pkrtz(a, b);
    return cv.u;
}

/* ---------------- kernel 1: pipelined shared-field MFMA histogram -----
 * Byte-identical to r14's best (76.3-77.3 us) and launched with
 * nchunk=64 -> 512 blocks = 2/CU (r15 proved 1/CU collapses overlap:
 * occupancy 16.5->10.4, main 77->97.5).
 * 256 thr / 4 waves, 32-px regions, dbuf LDS, one barrier per region,
 * T3 issue order {8 ds_reads -> gen under them -> 12-MFMA cluster},
 * setprio on MFMA clusters, b32 gen writes, mat2 gen in barrier shadow. */
__global__ __launch_bounds__(256, 2) void hist_mfma(
    const float* __restrict__ pred, const float* __restrict__ tgt,
    unsigned* __restrict__ parts, float* __restrict__ norms, int nchunk)
{
    __shared__ char smat[2 * BUFB];               /* 61440 B */
    __shared__ float wsumS[4];

    const int t    = threadIdx.x;
    const int lane = t & 63;
    const int wave = t >> 6;
    const int chunk = blockIdx.x % nchunk;
    const int ib    = blockIdx.x / nchunk;        /* img*4 + b */
    const int b     = ib & 3;
    const int img   = ib >> 2;
    const int kchunk = NPIX / nchunk;
    const int nreg   = kchunk >> 5;               /* 32-px regions, even */

    const float* __restrict__ base = (img ? tgt : pred) + (size_t)b * 3 * NPIX;
    const float* __restrict__ Rp = base;
    const float* __restrict__ Gp = base + NPIX;
    const float* __restrict__ Bp = base + 2 * NPIX;

    /* gen role */
    const int   i16     = lane & 15;              /* px pair index */
    const int   r4      = lane >> 4;              /* row within 16-group */
    const int   rowbase = wave * 4 + r4;          /* 0..15 */
    const float MU0     = (float)rowbase * (300.0f / 127.0f) - 150.0f;
    const float MUSTEP  = 16.0f * (300.0f / 127.0f);
    char* genp0 = smat + rowbase * ROWB + i16 * 4;
    char* genp1 = genp0 + BUFB;

    /* mfma role */
    const int ti2 = wave >> 1;
    const int tj2 = wave & 1;

    f32x16 acc[3][2][2];
#pragma unroll
    for (int g = 0; g < 3; ++g)
#pragma unroll
        for (int i = 0; i < 2; ++i)
#pragma unroll
            for (int j = 0; j < 2; ++j)
#pragma unroll
                for (int r = 0; r < 16; ++r) acc[g][i][j][r] = 0.0f;

    const int n0 = chunk * kchunk;

    f32x2 Ra, Ga, Ba, Rb, Gb, Bb;                 /* load ping-pong */
    f32x2 ddrg, ddrb, ddgb, rw2;                  /* current scalars */

    auto issue_ld = [&](int reg, f32x2& R, f32x2& G, f32x2& B) {
        const int n = n0 + reg * 32 + 2 * i16;
        R = *reinterpret_cast<const f32x2*>(Rp + n);
        G = *reinterpret_cast<const f32x2*>(Gp + n);
        B = *reinterpret_cast<const f32x2*>(Bp + n);
    };

    auto scalars = [&](f32x2 R, f32x2 G, f32x2 B) {
        const float C = 34.65735902799726547086f;   /* 50 * ln2 */
        float r0 = fminf(fmaxf(R.x, 0.0f), 1.0f);
        float r1 = fminf(fmaxf(R.y, 0.0f), 1.0f);
        float g0 = fminf(fmaxf(G.x, 0.0f), 1.0f);
        float g1 = fminf(fmaxf(G.y, 0.0f), 1.0f);
        float b0 = fminf(fmaxf(B.x, 0.0f), 1.0f);
        float b1 = fminf(fmaxf(B.y, 0.0f), 1.0f);
        float lr0 = __builtin_amdgcn_logf(r0 + EPSF);
        float lr1 = __builtin_amdgcn_logf(r1 + EPSF);
        float lg0 = __builtin_amdgcn_logf(g0 + EPSF);
        float lg1 = __builtin_amdgcn_logf(g1 + EPSF);
        float lb0 = __builtin_amdgcn_logf(b0 + EPSF);
        float lb1 = __builtin_amdgcn_logf(b1 + EPSF);
        ddrg.x = (lr0 - lg0) * C;  ddrg.y = (lr1 - lg1) * C;
        ddrb.x = (lr0 - lb0) * C;  ddrb.y = (lr1 - lb1) * C;
        ddgb.x = (lg0 - lb0) * C;  ddgb.y = (lg1 - lb1) * C;
        const float s0 = __builtin_fmaf(r0, r0,
                          __builtin_fmaf(g0, g0,
                           __builtin_fmaf(b0, b0, EPSF)));
        const float s1 = __builtin_fmaf(r1, r1,
                          __builtin_fmaf(g1, g1,
                           __builtin_fmaf(b1, b1, EPSF)));
        rw2.x = __builtin_amdgcn_sqrtf(__builtin_amdgcn_sqrtf(s0));
        rw2.y = __builtin_amdgcn_sqrtf(__builtin_amdgcn_sqrtf(s1));
    };

    auto gen_mat = [&](char* bp, int mat, f32x2 dd) {
        float m = MU0;
#pragma unroll
        for (int s = 0; s < 8; ++s) {              /* rows rowbase + 16*s */
            const float ex = dd.x - m, ey = dd.y - m;
            const float tx = __builtin_fmaf(ex, ex, 1.0f);
            const float ty = __builtin_fmaf(ey, ey, 1.0f);
            const float vx = __builtin_amdgcn_rcpf(tx) * rw2.x;
            const float vy = __builtin_amdgcn_rcpf(ty) * rw2.y;
            *reinterpret_cast<unsigned*>(bp + mat * MATB + s * 16 * ROWB)
                = pk2(vx, vy);
            m += MUSTEP;
        }
    };

    auto rd = [&](const char* mp, int matid, int row, int koff) -> half8 {
        return *reinterpret_cast<const half8*>(mp + matid * MATB
                                               + row * ROWB + koff);
    };

    /* region body, T3 order: reads -> gen under them -> MFMA cluster */
    auto body = [&](const char* mp, char* gp, bool dogen) {
        const int kbase = (lane >> 5) << 4;       /* 0 or 16 bytes */
        const int r0 = ti2 * 64 + (lane & 31);
        const int c0 = tj2 * 64 + (lane & 31);

        /* ---- k-step 0: 8 reads || gen mat0 || 12 MFMA ---- */
        {
            half8 a0  = rd(mp, 0, r0,      kbase);
            half8 a1  = rd(mp, 0, r0 + 32, kbase);
            half8 p0  = rd(mp, 1, c0,      kbase);
            half8 p1  = rd(mp, 1, c0 + 32, kbase);
            half8 q0  = rd(mp, 2, c0,      kbase);
            half8 q1  = rd(mp, 2, c0 + 32, kbase);
            half8 bb0 = rd(mp, 1, r0,      kbase);
            half8 bb1 = rd(mp, 1, r0 + 32, kbase);
            if (dogen) gen_mat(gp, 0, ddrg);
            __builtin_amdgcn_s_setprio(1);
            acc[0][0][0] = __builtin_amdgcn_mfma_f32_32x32x16_f16(a0, p0, acc[0][0][0], 0, 0, 0);
            acc[0][0][1] = __builtin_amdgcn_mfma_f32_32x32x16_f16(a0, p1, acc[0][0][1], 0, 0, 0);
            acc[0][1][0] = __builtin_amdgcn_mfma_f32_32x32x16_f16(a1, p0, acc[0][1][0], 0, 0, 0);
            acc[0][1][1] = __builtin_amdgcn_mfma_f32_32x32x16_f16(a1, p1, acc[0][1][1], 0, 0, 0);
            acc[1][0][0] = __builtin_amdgcn_mfma_f32_32x32x16_f16(a0, q0, acc[1][0][0], 0, 0, 0);
            acc[1][0][1] = __builtin_amdgcn_mfma_f32_32x32x16_f16(a0, q1, acc[1][0][1], 0, 0, 0);
            acc[1][1][0] = __builtin_amdgcn_mfma_f32_32x32x16_f16(a1, q0, acc[1][1][0], 0, 0, 0);
            acc[1][1][1] = __builtin_amdgcn_mfma_f32_32x32x16_f16(a1, q1, acc[1][1][1], 0, 0, 0);
            acc[2][0][0] = __builtin_amdgcn_mfma_f32_32x32x16_f16(bb0, q0, acc[2][0][0], 0, 0, 0);
            acc[2][0][1] = __builtin_amdgcn_mfma_f32_32x32x16_f16(bb0, q1, acc[2][0][1], 0, 0, 0);
            acc[2][1][0] = __builtin_amdgcn_mfma_f32_32x32x16_f16(bb1, q0, acc[2][1][0], 0, 0, 0);
            acc[2][1][1] = __builtin_amdgcn_mfma_f32_32x32x16_f16(bb1, q1, acc[2][1][1], 0, 0, 0);
            __builtin_amdgcn_s_setprio(0);
        }

        /* ---- k-step 1: 8 reads || gen mat1 || 12 MFMA ---- */
        {
            const int k1 = 32 + kbase;
            half8 a0  = rd(mp, 0, r0,      k1);
            half8 a1  = rd(mp, 0, r0 + 32, k1);
            half8 p0  = rd(mp, 1, c0,      k1);
            half8 p1  = rd(mp, 1, c0 + 32, k1);
            half8 q0  = rd(mp, 2, c0,      k1);
            half8 q1  = rd(mp, 2, c0 + 32, k1);
            half8 bb0 = rd(mp, 1, r0,      k1);
            half8 bb1 = rd(mp, 1, r0 + 32, k1);
            if (dogen) gen_mat(gp, 1, ddrb);
            __builtin_amdgcn_s_setprio(1);
            acc[0][0][0] = __builtin_amdgcn_mfma_f32_32x32x16_f16(a0, p0, acc[0][0][0], 0, 0, 0);
            acc[0][0][1] = __builtin_amdgcn_mfma_f32_32x32x16_f16(a0, p1, acc[0][0][1], 0, 0, 0);
            acc[0][1][0] = __builtin_amdgcn_mfma_f32_32x32x16_f16(a1, p0, acc[0][1][0], 0, 0, 0);
            acc[0][1][1] = __builtin_amdgcn_mfma_f32_32x32x16_f16(a1, p1, acc[0][1][1], 0, 0, 0);
            acc[1][0][0] = __builtin_amdgcn_mfma_f32_32x32x16_f16(a0, q0, acc[1][0][0], 0, 0, 0);
            acc[1][0][1] = __builtin_amdgcn_mfma_f32_32x32x16_f16(a0, q1, acc[1][0][1], 0, 0, 0);
            acc[1][1][0] = __builtin_amdgcn_mfma_f32_32x32x16_f16(a1, q0, acc[1][1][0], 0, 0, 0);
            acc[1][1][1] = __builtin_amdgcn_mfma_f32_32x32x16_f16(a1, q1, acc[1][1][1], 0, 0, 0);
            acc[2][0][0] = __builtin_amdgcn_mfma_f32_32x32x16_f16(bb0, q0, acc[2][0][0], 0, 0, 0);
            acc[2][0][1] = __builtin_amdgcn_mfma_f32_32x32x16_f16(bb0, q1, acc[2][0][1], 0, 0, 0);
            acc[2][1][0] = __builtin_amdgcn_mfma_f32_32x32x16_f16(bb1, q0, acc[2][1][0], 0, 0, 0);
            acc[2][1][1] = __builtin_amdgcn_mfma_f32_32x32x16_f16(bb1, q1, acc[2][1][1], 0, 0, 0);
            __builtin_amdgcn_s_setprio(0);
        }

        /* ---- tail: gen mat2 in the barrier shadow ---- */
        if (dogen) gen_mat(gp, 2, ddgb);
    };

    /* prologue: gen region 0 into buf0 */
    issue_ld(0, Ra, Ga, Ba);
    scalars(Ra, Ga, Ba);
    gen_mat(genp0, 0, ddrg);
    gen_mat(genp0, 1, ddrb);
    gen_mat(genp0, 2, ddgb);
    issue_ld(1, Rb, Gb, Bb);
    __syncthreads();

    for (int rg = 0; rg < nreg; rg += 2) {
        /* body A: MFMA reg rg (buf0) || gen reg rg+1 -> buf1 */
        scalars(Rb, Gb, Bb);
        issue_ld(min(rg + 2, nreg - 1), Ra, Ga, Ba);
        body(smat, genp1, true);
        __syncthreads();
        /* body B: MFMA reg rg+1 (buf1) || gen reg rg+2 -> buf0 */
        scalars(Ra, Ga, Ba);
        issue_ld(min(rg + 3, nreg - 1), Rb, Gb, Bb);
        body(smat + BUFB, genp0, rg + 2 < nreg);
        __syncthreads();
    }

    /* ---- epilogue A: pack f16 pairs, coalesced u32 stores.
     * word = (((g*4+wave)*2+i2)*2+j2)*8*64 + rh*64 + lane.
     * Consistent bijection; norms+Hellinger permutation-invariant. */
    unsigned* pb0 = parts + (size_t)blockIdx.x * PPW;
    float blksum = 0.0f;
#pragma unroll
    for (int g = 0; g < 3; ++g)
#pragma unroll
        for (int i2 = 0; i2 < 2; ++i2)
#pragma unroll
            for (int j2 = 0; j2 < 2; ++j2) {
                unsigned* wp = pb0
                    + (size_t)((((g * 4 + wave) * 2 + i2) * 2 + j2) * 8) * 64
                    + lane;
#pragma unroll
                for (int rh = 0; rh < 8; ++rh) {
                    wp[rh * 64] = pk2(acc[g][i2][j2][2 * rh],
                                      acc[g][i2][j2][2 * rh + 1]);
                    blksum += acc[g][i2][j2][2 * rh]
                            + acc[g][i2][j2][2 * rh + 1];
                }
            }

    /* ---- epilogue B: block contribution to norms[ib] ---- */
    for (int o = 32; o > 0; o >>= 1) blksum += __shfl_down(blksum, o, 64);
    if (lane == 0) wsumS[wave] = blksum;
    __syncthreads();
    if (t == 0)
        atomicAdd(&norms[ib], wsumS[0] + wsumS[1] + wsumS[2] + wsumS[3]);
}

/* ------- kernel 2: fused parts-reduce + Hellinger + loss + finalize ---
 * Last-block counter writes the final scalar (validated r13/r15). */
__global__ __launch_bounds__(256) void reduce_loss(
    const unsigned* __restrict__ parts, const float* __restrict__ norms,
    float* __restrict__ acc, unsigned* __restrict__ cnt,
    float* __restrict__ out, int nchunk)
{
    const int i      = blockIdx.x * 256 + threadIdx.x;  /* < 98304 */
    const int comb12 = i >> 13;                         /* block-uniform */
    const int rest   = i & 8191;
    const int b      = comb12 / 3;
    const int g      = comb12 % 3;
    const unsigned* pp = parts + (size_t)(b * nchunk) * PPW + g * 8192 + rest;
    const unsigned* pt = parts + (size_t)((4 + b) * nchunk) * PPW + g * 8192 + rest;

    float hp0 = 0.0f, hp1 = 0.0f, ht0 = 0.0f, ht1 = 0.0f;
    int k = 0;
    for (; k + 8 <= nchunk; k += 8) {
#pragma unroll
        for (int j = 0; j < 8; ++j) {
            union { unsigned u; fp16x2 h; } a, c;
            a.u = pp[(size_t)(k + j) * PPW];
            c.u = pt[(size_t)(k + j) * PPW];
            hp0 += (float)a.h.x;  hp1 += (float)a.h.y;
            ht0 += (float)c.h.x;  ht1 += (float)c.h.y;
        }
    }
    for (; k < nchunk; ++k) {
        union { unsigned u; fp16x2 h; } a, c;
        a.u = pp[(size_t)k * PPW];
        c.u = pt[(size_t)k * PPW];
        hp0 += (float)a.h.x;  hp1 += (float)a.h.y;
        ht0 += (float)c.h.x;  ht1 += (float)c.h.y;
    }

    const float rp = __builtin_amdgcn_rcpf(norms[b] + EPSF);
    const float rt = __builtin_amdgcn_rcpf(norms[4 + b] + EPSF);
    const float d0 = __builtin_amdgcn_sqrtf(ht0 * rt)
                   - __builtin_amdgcn_sqrtf(hp0 * rp);
    const float d1 = __builtin_amdgcn_sqrtf(ht1 * rt)
                   - __builtin_amdgcn_sqrtf(hp1 * rp);
    float s = __builtin_fmaf(d0, d0, d1 * d1);
    for (int o = 32; o > 0; o >>= 1) s += __shfl_down(s, o, 64);
    __shared__ float wsum[4];
    if ((threadIdx.x & 63) == 0) wsum[threadIdx.x >> 6] = s;
    __syncthreads();
    if (threadIdx.x == 0) {
        atomicAdd(acc, wsum[0] + wsum[1] + wsum[2] + wsum[3]);
        __threadfence();
        const unsigned done = atomicAdd(cnt, 1u);
        if (done == gridDim.x - 1) {
            const float v = atomicAdd(acc, 0.0f);   /* coherent read */
            out[0] = __builtin_amdgcn_sqrtf(v)
                   * 0.70710678118654752440f * 0.25f;
        }
    }
}

extern "C" void kernel_launch(void* const* d_in, const int* in_sizes, int n_in,
                              void* d_out, int out_size, void* d_ws, size_t ws_size,
                              hipStream_t stream)
{
    const float* pred = (const float*)d_in[0];
    const float* tgt  = (const float*)d_in[1];
    float* ws  = (float*)d_ws;
    float* out = (float*)d_out;

    float*    norms = ws;             /* 8 floats                          */
    float*    acc   = ws + 8;         /* 1 float                           */
    unsigned* cnt   = (unsigned*)(ws + 9);      /* 1 u32                   */
    unsigned* parts = (unsigned*)(ws + 16);     /* 8*nchunk*PPW u32        */

    /* nchunk=64 -> 512 blocks = 2/CU (measured optimum, r14/r15 A/B) */
    int nchunk = 64;
    while (nchunk > 1) {
        const size_t need = (16 + (size_t)8 * nchunk * PPW) * sizeof(float);
        if (need <= ws_size) break;
        nchunk >>= 1;
    }

    (void)hipMemsetAsync(ws, 0, 16 * sizeof(float), stream); /* norms+acc+cnt */

    hist_mfma<<<8 * nchunk, 256, 0, stream>>>(pred, tgt, parts, norms, nchunk);
    reduce_loss<<<12 * 8192 / 256, 256, 0, stream>>>(parts, norms, acc, cnt,
                                                     out, nchunk);
}

// Round 17
// 96.260 us; speedup vs baseline: 1.2008x; 1.0936x over previous
//
#include <hip/hip_runtime.h>

#define NPIX   65536
#define HB     128
#define EPSF   1e-6f
#define ROWB   80              /* 32 px * 2B = 64B data + 16B pad (5 x 16B) */
#define MATB   (HB * ROWB)     /* 10240 B per matrix */
#define BUFB   (3 * MATB)      /* 30720 B per buffer set */
#define PPW    24576           /* parts u32 words per block: 3*128*128/2 */

typedef _Float16 half8  __attribute__((ext_vector_type(8)));
typedef __fp16   fp16x2 __attribute__((ext_vector_type(2)));
typedef float    f32x16 __attribute__((ext_vector_type(16)));
typedef float    f32x2  __attribute__((ext_vector_type(2)));

__device__ __forceinline__ unsigned pk2(float a, float b) {
    union { fp16x2 h; unsigned u; } cv;
    cv.h = __builtin_amdgcn_cvt_pkrtz(a, b);
    return cv.u;
}

/* ---------------- kernel 1: pipelined shared-field MFMA histogram -----
 * Best-measured configuration (r14: 76.3-77.3 us main, 100.0 total).
 * 256 thr / 4 waves, nchunk=64 -> 512 blocks = 2/CU, 32-px regions,
 * dbuf LDS, one barrier per region, T3 issue order {8 ds_reads -> gen
 * under them -> 12-MFMA cluster}, setprio on MFMA clusters, b32 gen
 * writes, mat2 gen in barrier shadow, fused per-block norm reduction. */
__global__ __launch_bounds__(256, 2) void hist_mfma(
    const float* __restrict__ pred, const float* __restrict__ tgt,
    unsigned* __restrict__ parts, float* __restrict__ norms, int nchunk)
{
    __shared__ char smat[2 * BUFB];               /* 61440 B */
    __shared__ float wsumS[4];

    const int t    = threadIdx.x;
    const int lane = t & 63;
    const int wave = t >> 6;
    const int chunk = blockIdx.x % nchunk;
    const int ib    = blockIdx.x / nchunk;        /* img*4 + b */
    const int b     = ib & 3;
    const int img   = ib >> 2;
    const int kchunk = NPIX / nchunk;
    const int nreg   = kchunk >> 5;               /* 32-px regions, even */

    const float* __restrict__ base = (img ? tgt : pred) + (size_t)b * 3 * NPIX;
    const float* __restrict__ Rp = base;
    const float* __restrict__ Gp = base + NPIX;
    const float* __restrict__ Bp = base + 2 * NPIX;

    /* gen role */
    const int   i16     = lane & 15;              /* px pair index */
    const int   r4      = lane >> 4;              /* row within 16-group */
    const int   rowbase = wave * 4 + r4;          /* 0..15 */
    const float MU0     = (float)rowbase * (300.0f / 127.0f) - 150.0f;
    const float MUSTEP  = 16.0f * (300.0f / 127.0f);
    char* genp0 = smat + rowbase * ROWB + i16 * 4;
    char* genp1 = genp0 + BUFB;

    /* mfma role */
    const int ti2 = wave >> 1;
    const int tj2 = wave & 1;

    f32x16 acc[3][2][2];
#pragma unroll
    for (int g = 0; g < 3; ++g)
#pragma unroll
        for (int i = 0; i < 2; ++i)
#pragma unroll
            for (int j = 0; j < 2; ++j)
#pragma unroll
                for (int r = 0; r < 16; ++r) acc[g][i][j][r] = 0.0f;

    const int n0 = chunk * kchunk;

    f32x2 Ra, Ga, Ba, Rb, Gb, Bb;                 /* load ping-pong */
    f32x2 ddrg, ddrb, ddgb, rw2;                  /* current scalars */

    auto issue_ld = [&](int reg, f32x2& R, f32x2& G, f32x2& B) {
        const int n = n0 + reg * 32 + 2 * i16;
        R = *reinterpret_cast<const f32x2*>(Rp + n);
        G = *reinterpret_cast<const f32x2*>(Gp + n);
        B = *reinterpret_cast<const f32x2*>(Bp + n);
    };

    auto scalars = [&](f32x2 R, f32x2 G, f32x2 B) {
        const float C = 34.65735902799726547086f;   /* 50 * ln2 */
        float r0 = fminf(fmaxf(R.x, 0.0f), 1.0f);
        float r1 = fminf(fmaxf(R.y, 0.0f), 1.0f);
        float g0 = fminf(fmaxf(G.x, 0.0f), 1.0f);
        float g1 = fminf(fmaxf(G.y, 0.0f), 1.0f);
        float b0 = fminf(fmaxf(B.x, 0.0f), 1.0f);
        float b1 = fminf(fmaxf(B.y, 0.0f), 1.0f);
        float lr0 = __builtin_amdgcn_logf(r0 + EPSF);
        float lr1 = __builtin_amdgcn_logf(r1 + EPSF);
        float lg0 = __builtin_amdgcn_logf(g0 + EPSF);
        float lg1 = __builtin_amdgcn_logf(g1 + EPSF);
        float lb0 = __builtin_amdgcn_logf(b0 + EPSF);
        float lb1 = __builtin_amdgcn_logf(b1 + EPSF);
        ddrg.x = (lr0 - lg0) * C;  ddrg.y = (lr1 - lg1) * C;
        ddrb.x = (lr0 - lb0) * C;  ddrb.y = (lr1 - lb1) * C;
        ddgb.x = (lg0 - lb0) * C;  ddgb.y = (lg1 - lb1) * C;
        const float s0 = __builtin_fmaf(r0, r0,
                          __builtin_fmaf(g0, g0,
                           __builtin_fmaf(b0, b0, EPSF)));
        const float s1 = __builtin_fmaf(r1, r1,
                          __builtin_fmaf(g1, g1,
                           __builtin_fmaf(b1, b1, EPSF)));
        rw2.x = __builtin_amdgcn_sqrtf(__builtin_amdgcn_sqrtf(s0));
        rw2.y = __builtin_amdgcn_sqrtf(__builtin_amdgcn_sqrtf(s1));
    };

    auto gen_mat = [&](char* bp, int mat, f32x2 dd) {
        float m = MU0;
#pragma unroll
        for (int s = 0; s < 8; ++s) {              /* rows rowbase + 16*s */
            const float ex = dd.x - m, ey = dd.y - m;
            const float tx = __builtin_fmaf(ex, ex, 1.0f);
            const float ty = __builtin_fmaf(ey, ey, 1.0f);
            const float vx = __builtin_amdgcn_rcpf(tx) * rw2.x;
            const float vy = __builtin_amdgcn_rcpf(ty) * rw2.y;
            *reinterpret_cast<unsigned*>(bp + mat * MATB + s * 16 * ROWB)
                = pk2(vx, vy);
            m += MUSTEP;
        }
    };

    auto rd = [&](const char* mp, int matid, int row, int koff) -> half8 {
        return *reinterpret_cast<const half8*>(mp + matid * MATB
                                               + row * ROWB + koff);
    };

    /* region body, T3 order: reads -> gen under them -> MFMA cluster */
    auto body = [&](const char* mp, char* gp, bool dogen) {
        const int kbase = (lane >> 5) << 4;       /* 0 or 16 bytes */
        const int r0 = ti2 * 64 + (lane & 31);
        const int c0 = tj2 * 64 + (lane & 31);

        /* ---- k-step 0: 8 reads || gen mat0 || 12 MFMA ---- */
        {
            half8 a0  = rd(mp, 0, r0,      kbase);
            half8 a1  = rd(mp, 0, r0 + 32, kbase);
            half8 p0  = rd(mp, 1, c0,      kbase);
            half8 p1  = rd(mp, 1, c0 + 32, kbase);
            half8 q0  = rd(mp, 2, c0,      kbase);
            half8 q1  = rd(mp, 2, c0 + 32, kbase);
            half8 bb0 = rd(mp, 1, r0,      kbase);
            half8 bb1 = rd(mp, 1, r0 + 32, kbase);
            if (dogen) gen_mat(gp, 0, ddrg);
            __builtin_amdgcn_s_setprio(1);
            acc[0][0][0] = __builtin_amdgcn_mfma_f32_32x32x16_f16(a0, p0, acc[0][0][0], 0, 0, 0);
            acc[0][0][1] = __builtin_amdgcn_mfma_f32_32x32x16_f16(a0, p1, acc[0][0][1], 0, 0, 0);
            acc[0][1][0] = __builtin_amdgcn_mfma_f32_32x32x16_f16(a1, p0, acc[0][1][0], 0, 0, 0);
            acc[0][1][1] = __builtin_amdgcn_mfma_f32_32x32x16_f16(a1, p1, acc[0][1][1], 0, 0, 0);
            acc[1][0][0] = __builtin_amdgcn_mfma_f32_32x32x16_f16(a0, q0, acc[1][0][0], 0, 0, 0);
            acc[1][0][1] = __builtin_amdgcn_mfma_f32_32x32x16_f16(a0, q1, acc[1][0][1], 0, 0, 0);
            acc[1][1][0] = __builtin_amdgcn_mfma_f32_32x32x16_f16(a1, q0, acc[1][1][0], 0, 0, 0);
            acc[1][1][1] = __builtin_amdgcn_mfma_f32_32x32x16_f16(a1, q1, acc[1][1][1], 0, 0, 0);
            acc[2][0][0] = __builtin_amdgcn_mfma_f32_32x32x16_f16(bb0, q0, acc[2][0][0], 0, 0, 0);
            acc[2][0][1] = __builtin_amdgcn_mfma_f32_32x32x16_f16(bb0, q1, acc[2][0][1], 0, 0, 0);
            acc[2][1][0] = __builtin_amdgcn_mfma_f32_32x32x16_f16(bb1, q0, acc[2][1][0], 0, 0, 0);
            acc[2][1][1] = __builtin_amdgcn_mfma_f32_32x32x16_f16(bb1, q1, acc[2][1][1], 0, 0, 0);
            __builtin_amdgcn_s_setprio(0);
        }

        /* ---- k-step 1: 8 reads || gen mat1 || 12 MFMA ---- */
        {
            const int k1 = 32 + kbase;
            half8 a0  = rd(mp, 0, r0,      k1);
            half8 a1  = rd(mp, 0, r0 + 32, k1);
            half8 p0  = rd(mp, 1, c0,      k1);
            half8 p1  = rd(mp, 1, c0 + 32, k1);
            half8 q0  = rd(mp, 2, c0,      k1);
            half8 q1  = rd(mp, 2, c0 + 32, k1);
            half8 bb0 = rd(mp, 1, r0,      k1);
            half8 bb1 = rd(mp, 1, r0 + 32, k1);
            if (dogen) gen_mat(gp, 1, ddrb);
            __builtin_amdgcn_s_setprio(1);
            acc[0][0][0] = __builtin_amdgcn_mfma_f32_32x32x16_f16(a0, p0, acc[0][0][0], 0, 0, 0);
            acc[0][0][1] = __builtin_amdgcn_mfma_f32_32x32x16_f16(a0, p1, acc[0][0][1], 0, 0, 0);
            acc[0][1][0] = __builtin_amdgcn_mfma_f32_32x32x16_f16(a1, p0, acc[0][1][0], 0, 0, 0);
            acc[0][1][1] = __builtin_amdgcn_mfma_f32_32x32x16_f16(a1, p1, acc[0][1][1], 0, 0, 0);
            acc[1][0][0] = __builtin_amdgcn_mfma_f32_32x32x16_f16(a0, q0, acc[1][0][0], 0, 0, 0);
            acc[1][0][1] = __builtin_amdgcn_mfma_f32_32x32x16_f16(a0, q1, acc[1][0][1], 0, 0, 0);
            acc[1][1][0] = __builtin_amdgcn_mfma_f32_32x32x16_f16(a1, q0, acc[1][1][0], 0, 0, 0);
            acc[1][1][1] = __builtin_amdgcn_mfma_f32_32x32x16_f16(a1, q1, acc[1][1][1], 0, 0, 0);
            acc[2][0][0] = __builtin_amdgcn_mfma_f32_32x32x16_f16(bb0, q0, acc[2][0][0], 0, 0, 0);
            acc[2][0][1] = __builtin_amdgcn_mfma_f32_32x32x16_f16(bb0, q1, acc[2][0][1], 0, 0, 0);
            acc[2][1][0] = __builtin_amdgcn_mfma_f32_32x32x16_f16(bb1, q0, acc[2][1][0], 0, 0, 0);
            acc[2][1][1] = __builtin_amdgcn_mfma_f32_32x32x16_f16(bb1, q1, acc[2][1][1], 0, 0, 0);
            __builtin_amdgcn_s_setprio(0);
        }

        /* ---- tail: gen mat2 in the barrier shadow ---- */
        if (dogen) gen_mat(gp, 2, ddgb);
    };

    /* prologue: gen region 0 into buf0 */
    issue_ld(0, Ra, Ga, Ba);
    scalars(Ra, Ga, Ba);
    gen_mat(genp0, 0, ddrg);
    gen_mat(genp0, 1, ddrb);
    gen_mat(genp0, 2, ddgb);
    issue_ld(1, Rb, Gb, Bb);
    __syncthreads();

    for (int rg = 0; rg < nreg; rg += 2) {
        /* body A: MFMA reg rg (buf0) || gen reg rg+1 -> buf1 */
        scalars(Rb, Gb, Bb);
        issue_ld(min(rg + 2, nreg - 1), Ra, Ga, Ba);
        body(smat, genp1, true);
        __syncthreads();
        /* body B: MFMA reg rg+1 (buf1) || gen reg rg+2 -> buf0 */
        scalars(Ra, Ga, Ba);
        issue_ld(min(rg + 3, nreg - 1), Rb, Gb, Bb);
        body(smat + BUFB, genp0, rg + 2 < nreg);
        __syncthreads();
    }

    /* ---- epilogue A: pack f16 pairs, coalesced u32 stores.
     * word = (((g*4+wave)*2+i2)*2+j2)*8*64 + rh*64 + lane.
     * Consistent bijection; norms+Hellinger permutation-invariant. */
    unsigned* pb0 = parts + (size_t)blockIdx.x * PPW;
    float blksum = 0.0f;
#pragma unroll
    for (int g = 0; g < 3; ++g)
#pragma unroll
        for (int i2 = 0; i2 < 2; ++i2)
#pragma unroll
            for (int j2 = 0; j2 < 2; ++j2) {
                unsigned* wp = pb0
                    + (size_t)((((g * 4 + wave) * 2 + i2) * 2 + j2) * 8) * 64
                    + lane;
#pragma unroll
                for (int rh = 0; rh < 8; ++rh) {
                    wp[rh * 64] = pk2(acc[g][i2][j2][2 * rh],
                                      acc[g][i2][j2][2 * rh + 1]);
                    blksum += acc[g][i2][j2][2 * rh]
                            + acc[g][i2][j2][2 * rh + 1];
                }
            }

    /* ---- epilogue B: block contribution to norms[ib] ---- */
    for (int o = 32; o > 0; o >>= 1) blksum += __shfl_down(blksum, o, 64);
    if (lane == 0) wsumS[wave] = blksum;
    __syncthreads();
    if (t == 0)
        atomicAdd(&norms[ib], wsumS[0] + wsumS[1] + wsumS[2] + wsumS[3]);
}

/* ------- kernel 2: fused parts-reduce + Hellinger + loss -------------- */
__global__ __launch_bounds__(256) void reduce_loss(
    const unsigned* __restrict__ parts, const float* __restrict__ norms,
    float* __restrict__ acc, int nchunk)
{
    const int i      = blockIdx.x * 256 + threadIdx.x;  /* < 98304 */
    const int comb12 = i >> 13;                         /* block-uniform */
    const int rest   = i & 8191;
    const int b      = comb12 / 3;
    const int g      = comb12 % 3;
    const unsigned* pp = parts + (size_t)(b * nchunk) * PPW + g * 8192 + rest;
    const unsigned* pt = parts + (size_t)((4 + b) * nchunk) * PPW + g * 8192 + rest;

    float hp0 = 0.0f, hp1 = 0.0f, ht0 = 0.0f, ht1 = 0.0f;
    int k = 0;
    for (; k + 8 <= nchunk; k += 8) {
#pragma unroll
        for (int j = 0; j < 8; ++j) {
            union { unsigned u; fp16x2 h; } a, c;
            a.u = pp[(size_t)(k + j) * PPW];
            c.u = pt[(size_t)(k + j) * PPW];
            hp0 += (float)a.h.x;  hp1 += (float)a.h.y;
            ht0 += (float)c.h.x;  ht1 += (float)c.h.y;
        }
    }
    for (; k < nchunk; ++k) {
        union { unsigned u; fp16x2 h; } a, c;
        a.u = pp[(size_t)k * PPW];
        c.u = pt[(size_t)k * PPW];
        hp0 += (float)a.h.x;  hp1 += (float)a.h.y;
        ht0 += (float)c.h.x;  ht1 += (float)c.h.y;
    }

    const float rp = __builtin_amdgcn_rcpf(norms[b] + EPSF);
    const float rt = __builtin_amdgcn_rcpf(norms[4 + b] + EPSF);
    const float d0 = __builtin_amdgcn_sqrtf(ht0 * rt)
                   - __builtin_amdgcn_sqrtf(hp0 * rp);
    const float d1 = __builtin_amdgcn_sqrtf(ht1 * rt)
                   - __builtin_amdgcn_sqrtf(hp1 * rp);
    float s = __builtin_fmaf(d0, d0, d1 * d1);
    for (int o = 32; o > 0; o >>= 1) s += __shfl_down(s, o, 64);
    __shared__ float wsum[4];
    if ((threadIdx.x & 63) == 0) wsum[threadIdx.x >> 6] = s;
    __syncthreads();
    if (threadIdx.x == 0) atomicAdd(acc, wsum[0] + wsum[1] + wsum[2] + wsum[3]);
}

/* ---------------- kernel 3: final scalar ------------------------------ */
__global__ void final_k(const float* __restrict__ acc, float* __restrict__ out)
{
    out[0] = __builtin_amdgcn_sqrtf(acc[0]) * 0.70710678118654752440f * 0.25f;
}

extern "C" void kernel_launch(void* const* d_in, const int* in_sizes, int n_in,
                              void* d_out, int out_size, void* d_ws, size_t ws_size,
                              hipStream_t stream)
{
    const float* pred = (const float*)d_in[0];
    const float* tgt  = (const float*)d_in[1];
    float* ws  = (float*)d_ws;
    float* out = (float*)d_out;

    float*    norms = ws;             /* 8 floats                          */
    float*    acc   = ws + 8;         /* 1 float                           */
    unsigned* parts = (unsigned*)(ws + 16);     /* 8*nchunk*PPW u32        */

    /* nchunk=64 -> 512 blocks = 2/CU (measured optimum, r14/r15 A/B) */
    int nchunk = 64;
    while (nchunk > 1) {
        const size_t need = (16 + (size_t)8 * nchunk * PPW) * sizeof(float);
        if (need <= ws_size) break;
        nchunk >>= 1;
    }

    (void)hipMemsetAsync(ws, 0, 16 * sizeof(float), stream);  /* norms+acc */

    hist_mfma<<<8 * nchunk, 256, 0, stream>>>(pred, tgt, parts, norms, nchunk);
    reduce_loss<<<12 * 8192 / 256, 256, 0, stream>>>(parts, norms, acc, nchunk);
    final_k<<<1, 1, 0, stream>>>(acc, out);
}